// Round 4
// baseline (433.846 us; speedup 1.0000x reference)
//
#include <hip/hip_runtime.h>

#define NB 16
#define NN 1024
#define NBN (NB * NN)
#define MAXN 128
#define NU 8
#define NH 12
#define NMLP 16
#define KC 16
#define NCHUNK (NN / KC)  // 64

// word offset of 8-byte granule h (h=0..7) of row j in hsT.
// XOR swizzle: staging writes conflict-free (16 consecutive j cover all 32
// banks exactly once); random-j b64 gathers spread over 16 bank-groups
// (avg 4-way ~1.43x) instead of 8 groups with 16B granules (8-way ~2.9x).
#define GSW(j, h) (((j) << 4) + ((((h) ^ ((j) >> 1)) & 7) << 1))

// ---------------------------------------------------------------------------
// Kernel 1: scan adjacency rows -> transposed neighbor lists idxT[t][row]
// (uint16), cnt, deg; also zeroes the fp32 atomic accumulators eg/yh/hh.
// ---------------------------------------------------------------------------
__global__ __launch_bounds__(256) void k_build_idx(
    const float* __restrict__ adj, unsigned short* __restrict__ idxT,
    int* __restrict__ cnt, float* __restrict__ deg,
    float* __restrict__ eg, float* __restrict__ yh, float* __restrict__ hh) {
  const int row = blockIdx.x * 4 + (threadIdx.x >> 6);
  const int lane = threadIdx.x & 63;
  const float4* arow = (const float4*)(adj + (size_t)row * NN);
  float4 v[4];
#pragma unroll
  for (int rep = 0; rep < 4; ++rep) v[rep] = arow[rep * 64 + lane];  // ILP
  const unsigned long long ltmask = (1ull << lane) - 1ull;
  int base = 0;
#pragma unroll
  for (int rep = 0; rep < 4; ++rep) {
    float c[4] = {v[rep].x, v[rep].y, v[rep].z, v[rep].w};
#pragma unroll
    for (int cc = 0; cc < 4; ++cc) {
      bool nz = (c[cc] != 0.0f);
      unsigned long long m = __ballot(nz);
      if (nz) {
        int p = base + __popcll(m & ltmask);
        if (p < MAXN)
          idxT[(size_t)p * NBN + row] = (unsigned short)(rep * 256 + lane * 4 + cc);
      }
      base += __popcll(m);
    }
  }
  if (lane == 0) {
    cnt[row] = base < MAXN ? base : MAXN;
    deg[row] = (float)base;
    eg[row] = 0.f; yh[row] = 0.f; hh[row] = 0.f;
  }
}

// ---------------------------------------------------------------------------
// Kernel 2: per (b, chunk of 16 H-rows): stage transposed+swizzled in LDS.
//  - yh/hh partials (conflict-free b64 row reads, atomics)
//  - eg partials, lane-owns-i: hi in registers, per neighbor 8x ds_read_b64
// ---------------------------------------------------------------------------
__global__ __launch_bounds__(512) void k_eg(
    const float* __restrict__ H, const float* __restrict__ y,
    const unsigned short* __restrict__ idxT, const int* __restrict__ cnt,
    float* __restrict__ eg, float* __restrict__ yh, float* __restrict__ hh) {
  __shared__ float hsT[NN * KC];  // 64 KB
  const int b = blockIdx.x >> 6;
  const int k0 = (blockIdx.x & 63) * KC;
  const int tid = threadIdx.x;
  const float* Hb = H + ((size_t)b * NN + k0) * NN;

  // stage transposed: 16 coalesced scalar loads -> 8 b64 LDS writes per col
  for (int j0 = tid; j0 < NN; j0 += 512) {
    float hv[KC];
#pragma unroll
    for (int k = 0; k < KC; ++k) hv[k] = Hb[(size_t)k * NN + j0];
#pragma unroll
    for (int h = 0; h < 8; ++h)
      *(float2*)&hsT[GSW(j0, h)] = make_float2(hv[2 * h], hv[2 * h + 1]);
  }
  __syncthreads();

  // yh / hh partials
  {
    float yv[KC];
#pragma unroll
    for (int k = 0; k < KC; ++k) yv[k] = y[b * NN + k0 + k];
    for (int j = tid; j < NN; j += 512) {
      float py = 0.f, ph = 0.f;
#pragma unroll
      for (int h = 0; h < 8; ++h) {
        float2 hv = *(const float2*)&hsT[GSW(j, h)];
        py += yv[2 * h] * hv.x + yv[2 * h + 1] * hv.y;
        ph += hv.x * hv.x + hv.y * hv.y;
      }
      atomicAdd(&yh[b * NN + j], py);
      atomicAdd(&hh[b * NN + j], ph);
    }
  }

  // eg partials: lane owns i (consecutive i per lane -> coalesced idx reads)
  for (int rep = 0; rep < 2; ++rep) {
    const int i = rep * 512 + tid;
    const int node = b * NN + i;
    const int nnz = cnt[node];
    float2 hi2[8];
#pragma unroll
    for (int h = 0; h < 8; ++h) hi2[h] = *(const float2*)&hsT[GSW(i, h)];
    float a0 = 0.f, a1 = 0.f, a2 = 0.f, a3 = 0.f;
    int jcur = (nnz > 0) ? (int)idxT[node] : 0;
    for (int t = 0; t < nnz; ++t) {
      int jnext = (t + 1 < nnz) ? (int)idxT[(size_t)(t + 1) * NBN + node] : 0;
      float2 hj[8];
#pragma unroll
      for (int h = 0; h < 8; ++h) hj[h] = *(const float2*)&hsT[GSW(jcur, h)];
      a0 += hi2[0].x * hj[0].x + hi2[0].y * hj[0].y
          + hi2[1].x * hj[1].x + hi2[1].y * hj[1].y;
      a1 += hi2[2].x * hj[2].x + hi2[2].y * hj[2].y
          + hi2[3].x * hj[3].x + hi2[3].y * hj[3].y;
      a2 += hi2[4].x * hj[4].x + hi2[4].y * hj[4].y
          + hi2[5].x * hj[5].x + hi2[5].y * hj[5].y;
      a3 += hi2[6].x * hj[6].x + hi2[6].y * hj[6].y
          + hi2[7].x * hj[7].x + hi2[7].y * hj[7].y;
      jcur = jnext;
    }
    atomicAdd(&eg[node], (a0 + a1) + (a2 + a3));
  }
}

// ---------------------------------------------------------------------------
// Kernel 3: u0 = [yh, hh] @ W1^T + W1_b + b1
// ---------------------------------------------------------------------------
__global__ __launch_bounds__(256) void k_u0(
    const float* __restrict__ yh, const float* __restrict__ hh,
    const float* __restrict__ W1w, const float* __restrict__ W1b,
    const float* __restrict__ b1, float* __restrict__ u) {
  const int t = blockIdx.x * 256 + threadIdx.x;  // b*NN + j
  const float a = yh[t], c = hh[t];
#pragma unroll
  for (int o = 0; o < NU; ++o)
    u[(size_t)t * NU + o] = a * W1w[2 * o] + c * W1w[2 * o + 1] + W1b[o] + b1[o];
}

// ---------------------------------------------------------------------------
// Kernel 4: fused neighbor-gather + msg-MLP + GRU + W2 (+ optional readout).
// One 64-thread block per CU-worth of nodes; thread per node.
// u is double-buffered across iterations (no intra-kernel global sync).
// ---------------------------------------------------------------------------
__global__ __launch_bounds__(64) void k_iter(
    const float* __restrict__ u_in, const unsigned short* __restrict__ idxT,
    const int* __restrict__ cnt,
    const float* __restrict__ deg, const float* __restrict__ eg,
    const float* __restrict__ rin, const float* __restrict__ nur,
    const float* __restrict__ Wm1w, const float* __restrict__ Wm1b,
    const float* __restrict__ Wm2w, const float* __restrict__ Wm2b,
    const float* __restrict__ gih, const float* __restrict__ ghh,
    const float* __restrict__ bih, const float* __restrict__ bhh,
    const float* __restrict__ W2w, const float* __restrict__ W2b,
    const float* __restrict__ b2,
    const float* __restrict__ Wr1w, const float* __restrict__ Wr1b,
    const float* __restrict__ Wr2w, const float* __restrict__ Wr2b,
    float* __restrict__ s, float* __restrict__ u_out, float* __restrict__ out,
    int first, int readout) {
  __shared__ float sWm1[NMLP * 3 * NU], sWm1b[NMLP], sWm2[NU * NMLP], sWm2b[NU];
  __shared__ float sgih[36 * (NU + 2)], sghh[36 * NH], sbih[36], sbhh[36];
  __shared__ float sW2[NU * NH], sW2b[NU], sb2[NU];
  __shared__ float sWr1[NMLP * NU], sWr1b[NMLP], sWr2[2 * NMLP], sWr2b[2];
  {
    auto cp = [&](float* d, const float* so, int n) {
      for (int t = threadIdx.x; t < n; t += 64) d[t] = so[t];
    };
    cp(sWm1, Wm1w, NMLP * 3 * NU); cp(sWm1b, Wm1b, NMLP);
    cp(sWm2, Wm2w, NU * NMLP);     cp(sWm2b, Wm2b, NU);
    cp(sgih, gih, 36 * (NU + 2));  cp(sghh, ghh, 36 * NH);
    cp(sbih, bih, 36);             cp(sbhh, bhh, 36);
    cp(sW2, W2w, NU * NH);         cp(sW2b, W2b, NU);   cp(sb2, b2, NU);
    cp(sWr1, Wr1w, NMLP * NU);     cp(sWr1b, Wr1b, NMLP);
    cp(sWr2, Wr2w, 2 * NMLP);      cp(sWr2b, Wr2b, 2);
  }
  __syncthreads();
  const int node = blockIdx.x * 64 + threadIdx.x;

  // ---- neighbor gather: msum = sum_{j in N(node)} u_in[b,j,:]
  const int nnz = cnt[node];
  const float* ub = u_in + (size_t)(node & ~(NN - 1)) * NU;  // batch base
  float4 acc0 = {0, 0, 0, 0}, acc1 = {0, 0, 0, 0};
  int j = (nnz > 0) ? (int)idxT[node] : 0;
  for (int t = 0; t < nnz; ++t) {
    int jn = (t + 1 < nnz) ? (int)idxT[(size_t)(t + 1) * NBN + node] : 0;
    const float4* up = (const float4*)(ub + (size_t)j * NU);
    float4 a = up[0], c4 = up[1];
    acc0.x += a.x;  acc0.y += a.y;  acc0.z += a.z;  acc0.w += a.w;
    acc1.x += c4.x; acc1.y += c4.y; acc1.z += c4.z; acc1.w += c4.w;
    j = jn;
  }
  const float msv[NU] = {acc0.x, acc0.y, acc0.z, acc0.w,
                         acc1.x, acc1.y, acc1.z, acc1.w};

  // ---- msg MLP
  float agg[3 * NU];
  const float d = deg[node], e = eg[node];
#pragma unroll
  for (int o = 0; o < NU; ++o) {
    agg[o] = u_in[(size_t)node * NU + o] * d;
    agg[NU + o] = msv[o];
    agg[2 * NU + o] = e;
  }
  float h1[NMLP];
#pragma unroll
  for (int h = 0; h < NMLP; ++h) {
    float t = sWm1b[h];
#pragma unroll
    for (int i = 0; i < 3 * NU; ++i) t += sWm1[h * 3 * NU + i] * agg[i];
    h1[h] = fmaxf(t, 0.f);
  }
  float x[NU + 2];
#pragma unroll
  for (int o = 0; o < NU; ++o) {
    float t = sWm2b[o];
#pragma unroll
    for (int h = 0; h < NMLP; ++h) t += sWm2[o * NMLP + h] * h1[h];
    x[o] = t;
  }
  x[NU] = rin[node];
  x[NU + 1] = fmaxf(nur[node], 1e-10f);

  // ---- GRU
  float sv[NH];
#pragma unroll
  for (int g = 0; g < NH; ++g) sv[g] = first ? 0.f : s[(size_t)node * NH + g];

  float sn[NH];
#pragma unroll
  for (int g = 0; g < NH; ++g) {
    float xr = sbih[g], xz = sbih[NH + g], xn = sbih[2 * NH + g];
#pragma unroll
    for (int i = 0; i < NU + 2; ++i) {
      xr += sgih[g * (NU + 2) + i] * x[i];
      xz += sgih[(NH + g) * (NU + 2) + i] * x[i];
      xn += sgih[(2 * NH + g) * (NU + 2) + i] * x[i];
    }
    float hr = sbhh[g], hz = sbhh[NH + g], hn = sbhh[2 * NH + g];
    if (!first) {
#pragma unroll
      for (int i = 0; i < NH; ++i) {
        hr += sghh[g * NH + i] * sv[i];
        hz += sghh[(NH + g) * NH + i] * sv[i];
        hn += sghh[(2 * NH + g) * NH + i] * sv[i];
      }
    }
    float rg = 1.f / (1.f + expf(-(xr + hr)));
    float zg = 1.f / (1.f + expf(-(xz + hz)));
    float ng = tanhf(xn + rg * hn);
    sn[g] = (1.f - zg) * ng + zg * sv[g];
  }
#pragma unroll
  for (int g = 0; g < NH; ++g) s[(size_t)node * NH + g] = sn[g];

  // ---- W2
  float un[NU];
#pragma unroll
  for (int o = 0; o < NU; ++o) {
    float t = sW2b[o] + sb2[o];
#pragma unroll
    for (int h = 0; h < NH; ++h) t += sW2[o * NH + h] * sn[h];
    un[o] = t;
    u_out[(size_t)node * NU + o] = t;
  }

  // ---- readout (last iteration only)
  if (readout) {
    float h2[NMLP];
#pragma unroll
    for (int h = 0; h < NMLP; ++h) {
      float t = sWr1b[h];
#pragma unroll
      for (int o = 0; o < NU; ++o) t += sWr1[h * NU + o] * un[o];
      h2[h] = fmaxf(t, 0.f);
    }
    float l0 = sWr2b[0], l1 = sWr2b[1];
#pragma unroll
    for (int h = 0; h < NMLP; ++h) {
      l0 += sWr2[h] * h2[h];
      l1 += sWr2[NMLP + h] * h2[h];
    }
    float mx = fmaxf(l0, l1);
    float e0 = expf(l0 - mx), e1 = expf(l1 - mx);
    float inv = 1.f / (e0 + e1);
    float p0 = e0 * inv, p1 = e1 * inv;
    const float q0 = -0.70710678118654752f, q1 = 0.70710678118654752f;
    float xh = p0 * q0 + p1 * q1;
    float nu = p0 * (q0 - xh) * (q0 - xh) + p1 * (q1 - xh) * (q1 - xh);
    out[node] = xh;
    out[NB * NN + node] = fmaxf(nu, 1e-10f);
  }
}

// ---------------------------------------------------------------------------
extern "C" void kernel_launch(void* const* d_in, const int* in_sizes, int n_in,
                              void* d_out, int out_size, void* d_ws,
                              size_t ws_size, hipStream_t stream) {
  const float* y    = (const float*)d_in[0];
  const float* H    = (const float*)d_in[1];
  const float* r    = (const float*)d_in[2];
  const float* nur  = (const float*)d_in[3];
  const float* adj  = (const float*)d_in[4];
  const float* W1w  = (const float*)d_in[5];
  const float* W1b  = (const float*)d_in[6];
  const float* b1   = (const float*)d_in[7];
  const float* Wm1w = (const float*)d_in[8];
  const float* Wm1b = (const float*)d_in[9];
  const float* Wm2w = (const float*)d_in[10];
  const float* Wm2b = (const float*)d_in[11];
  const float* gih  = (const float*)d_in[12];
  const float* ghh  = (const float*)d_in[13];
  const float* bih  = (const float*)d_in[14];
  const float* bhh  = (const float*)d_in[15];
  const float* W2w  = (const float*)d_in[16];
  const float* W2b  = (const float*)d_in[17];
  const float* b2   = (const float*)d_in[18];
  const float* Wr1w = (const float*)d_in[19];
  const float* Wr1b = (const float*)d_in[20];
  const float* Wr2w = (const float*)d_in[21];
  const float* Wr2b = (const float*)d_in[22];
  float* out = (float*)d_out;

  // workspace carve (all 256B aligned)
  char* p = (char*)d_ws;
  auto carve = [&](size_t bytes) {
    void* q = (void*)p;
    p += (bytes + 255) & ~(size_t)255;
    return q;
  };
  unsigned short* idxT = (unsigned short*)carve((size_t)MAXN * NBN * 2);  // 4 MB
  int*   cnt  = (int*)  carve((size_t)NBN * 4);
  float* deg  = (float*)carve((size_t)NBN * 4);
  float* eg   = (float*)carve((size_t)NBN * 4);
  float* yh   = (float*)carve((size_t)NBN * 4);
  float* hh   = (float*)carve((size_t)NBN * 4);
  float* ua   = (float*)carve((size_t)NBN * NU * 4);
  float* ub   = (float*)carve((size_t)NBN * NU * 4);
  float* s    = (float*)carve((size_t)NBN * NH * 4);

  k_build_idx<<<NBN / 4, 256, 0, stream>>>(adj, idxT, cnt, deg, eg, yh, hh);
  k_eg<<<NB * NCHUNK, 512, 0, stream>>>(H, y, idxT, cnt, eg, yh, hh);
  k_u0<<<NBN / 256, 256, 0, stream>>>(yh, hh, W1w, W1b, b1, ua);

  k_iter<<<NBN / 64, 64, 0, stream>>>(
      ua, idxT, cnt, deg, eg, r, nur, Wm1w, Wm1b, Wm2w, Wm2b, gih, ghh, bih,
      bhh, W2w, W2b, b2, Wr1w, Wr1b, Wr2w, Wr2b, s, ub, out,
      /*first=*/1, /*readout=*/0);
  k_iter<<<NBN / 64, 64, 0, stream>>>(
      ub, idxT, cnt, deg, eg, r, nur, Wm1w, Wm1b, Wm2w, Wm2b, gih, ghh, bih,
      bhh, W2w, W2b, b2, Wr1w, Wr1b, Wr2w, Wr2b, s, ua, out,
      /*first=*/0, /*readout=*/1);
}

// Round 5
// 348.082 us; speedup vs baseline: 1.2464x; 1.2464x over previous
//
#include <hip/hip_runtime.h>

#define NB 16
#define NN 1024
#define NBN (NB * NN)
#define MAXN 128
#define NU 8
#define NH 12
#define NMLP 16
#define KC 16
#define NCHUNK (NN / KC)  // 64

// swizzled float4-quadrant slot within hsT: row j (16 floats), quadrant c.
// staging/row reads: 64 consecutive j spread uniformly over 8 bank-groups
// (optimal 8-cyc b128 floor); random-j gather ~1.6x multinomial tail.
// (round-4 lesson: 8B granules with 16 groups measured WORSE - do not retry)
#define QSW(j, c) (((j) << 4) + ((((c) ^ (((j) >> 2) & 3)) & 3) << 2))

// ---------------------------------------------------------------------------
// Kernel 1: scan adjacency rows -> transposed neighbor lists idxT[t][row]
// (uint16), cnt, deg; zeroes the fp32 atomic accumulators eg/yhh.
// ---------------------------------------------------------------------------
__global__ __launch_bounds__(256) void k_build_idx(
    const float* __restrict__ adj, unsigned short* __restrict__ idxT,
    int* __restrict__ cnt, float* __restrict__ deg,
    float* __restrict__ eg, float* __restrict__ yhh) {
  const int row = blockIdx.x * 4 + (threadIdx.x >> 6);
  const int lane = threadIdx.x & 63;
  const float4* arow = (const float4*)(adj + (size_t)row * NN);
  float4 v[4];
#pragma unroll
  for (int rep = 0; rep < 4; ++rep) v[rep] = arow[rep * 64 + lane];  // ILP
  const unsigned long long ltmask = (1ull << lane) - 1ull;
  int base = 0;
#pragma unroll
  for (int rep = 0; rep < 4; ++rep) {
    float c[4] = {v[rep].x, v[rep].y, v[rep].z, v[rep].w};
#pragma unroll
    for (int cc = 0; cc < 4; ++cc) {
      bool nz = (c[cc] != 0.0f);
      unsigned long long m = __ballot(nz);
      if (nz) {
        int p = base + __popcll(m & ltmask);
        if (p < MAXN)
          idxT[(size_t)p * NBN + row] = (unsigned short)(rep * 256 + lane * 4 + cc);
      }
      base += __popcll(m);
    }
  }
  if (lane == 0) {
    cnt[row] = base < MAXN ? base : MAXN;
    deg[row] = (float)base;
    eg[row] = 0.f; yhh[2 * row] = 0.f; yhh[2 * row + 1] = 0.f;
  }
}

// ---------------------------------------------------------------------------
// Kernel 2: per (b, chunk of 16 H-rows): stage transposed+swizzled in LDS.
//  - yh/hh partials (uniform-spread b128 row reads, atomics, interleaved)
//  - eg partials, lane-owns-i: hi in registers, per neighbor 4x ds_read_b128
// ---------------------------------------------------------------------------
__global__ __launch_bounds__(512) void k_eg(
    const float* __restrict__ H, const float* __restrict__ y,
    const unsigned short* __restrict__ idxT, const int* __restrict__ cnt,
    float* __restrict__ eg, float* __restrict__ yhh) {
  __shared__ float hsT[NN * KC];  // 64 KB
  const int b = blockIdx.x >> 6;
  const int k0 = (blockIdx.x & 63) * KC;
  const int tid = threadIdx.x;
  const float* Hb = H + ((size_t)b * NN + k0) * NN;

  // stage transposed: 16 coalesced scalar loads -> 4 b128 LDS writes per col
  for (int j0 = tid; j0 < NN; j0 += 512) {
    float hv[KC];
#pragma unroll
    for (int k = 0; k < KC; ++k) hv[k] = Hb[(size_t)k * NN + j0];
#pragma unroll
    for (int c = 0; c < 4; ++c)
      *(float4*)&hsT[QSW(j0, c)] = ((const float4*)hv)[c];
  }
  __syncthreads();

  // yh / hh partials
  {
    float yv[KC];
#pragma unroll
    for (int k = 0; k < KC; ++k) yv[k] = y[b * NN + k0 + k];
    for (int j = tid; j < NN; j += 512) {
      float hv[KC];
#pragma unroll
      for (int c = 0; c < 4; ++c)
        ((float4*)hv)[c] = *(const float4*)&hsT[QSW(j, c)];
      float py = 0.f, ph = 0.f;
#pragma unroll
      for (int k = 0; k < KC; ++k) { py += yv[k] * hv[k]; ph += hv[k] * hv[k]; }
      atomicAdd(&yhh[(b * NN + j) * 2], py);
      atomicAdd(&yhh[(b * NN + j) * 2 + 1], ph);
    }
  }

  // eg partials: lane owns i (consecutive i per lane -> coalesced idx reads)
  for (int rep = 0; rep < 2; ++rep) {
    const int i = rep * 512 + tid;
    const int node = b * NN + i;
    const int nnz = cnt[node];
    float hi[KC];
#pragma unroll
    for (int c = 0; c < 4; ++c)
      ((float4*)hi)[c] = *(const float4*)&hsT[QSW(i, c)];
    float a0 = 0.f, a1 = 0.f, a2 = 0.f, a3 = 0.f;
#pragma unroll 2
    for (int t = 0; t < nnz; ++t) {
      const int j = (int)idxT[(size_t)t * NBN + node];
      float hj[KC];
#pragma unroll
      for (int c = 0; c < 4; ++c)
        ((float4*)hj)[c] = *(const float4*)&hsT[QSW(j, c)];
#pragma unroll
      for (int k = 0; k < 4; ++k) {
        a0 += hi[k] * hj[k];
        a1 += hi[4 + k] * hj[4 + k];
        a2 += hi[8 + k] * hj[8 + k];
        a3 += hi[12 + k] * hj[12 + k];
      }
    }
    atomicAdd(&eg[node], (a0 + a1) + (a2 + a3));
  }
}

// ---------------------------------------------------------------------------
// Kernel 3: fused neighbor-gather + msg-MLP + GRU (+ readout on PHASE 2).
// PHASE 1: u0 is linear in (yh,hh) -> gather collapses to (sum yh, sum hh);
//          own u0 computed in-register; writes s and u.
// PHASE 2: gathers u (32 B/neighbor, unroll-4); reads s; writes out.
// ---------------------------------------------------------------------------
template <int PHASE>
__global__ __launch_bounds__(64) void k_iter(
    const float* __restrict__ u_in, const float2* __restrict__ yhh,
    const unsigned short* __restrict__ idxT, const int* __restrict__ cnt,
    const float* __restrict__ deg, const float* __restrict__ eg,
    const float* __restrict__ rin, const float* __restrict__ nur,
    const float* __restrict__ W1w, const float* __restrict__ W1b,
    const float* __restrict__ b1,
    const float* __restrict__ Wm1w, const float* __restrict__ Wm1b,
    const float* __restrict__ Wm2w, const float* __restrict__ Wm2b,
    const float* __restrict__ gih, const float* __restrict__ ghh,
    const float* __restrict__ bih, const float* __restrict__ bhh,
    const float* __restrict__ W2w, const float* __restrict__ W2b,
    const float* __restrict__ b2,
    const float* __restrict__ Wr1w, const float* __restrict__ Wr1b,
    const float* __restrict__ Wr2w, const float* __restrict__ Wr2b,
    float* __restrict__ s, float* __restrict__ u_out, float* __restrict__ out) {
  __shared__ float sWm1[NMLP * 3 * NU], sWm1b[NMLP], sWm2[NU * NMLP], sWm2b[NU];
  __shared__ float sgih[36 * (NU + 2)], sghh[36 * NH], sbih[36], sbhh[36];
  __shared__ float sW2[NU * NH], sW2b[NU], sb2[NU];
  __shared__ float sWr1[NMLP * NU], sWr1b[NMLP], sWr2[2 * NMLP], sWr2b[2];
  __shared__ float sW1[2 * NU], sWb1[NU];
  {
    auto cp = [&](float* d, const float* so, int n) {
      for (int t = threadIdx.x; t < n; t += 64) d[t] = so[t];
    };
    cp(sWm1, Wm1w, NMLP * 3 * NU); cp(sWm1b, Wm1b, NMLP);
    cp(sWm2, Wm2w, NU * NMLP);     cp(sWm2b, Wm2b, NU);
    cp(sgih, gih, 36 * (NU + 2));
    cp(sbih, bih, 36);             cp(sbhh, bhh, 36);
    cp(sW2, W2w, NU * NH);         cp(sW2b, W2b, NU);   cp(sb2, b2, NU);
    if (PHASE == 1) {
      cp(sW1, W1w, 2 * NU);
      for (int t = threadIdx.x; t < NU; t += 64) sWb1[t] = W1b[t] + b1[t];
    } else {
      cp(sghh, ghh, 36 * NH);
      cp(sWr1, Wr1w, NMLP * NU);   cp(sWr1b, Wr1b, NMLP);
      cp(sWr2, Wr2w, 2 * NMLP);    cp(sWr2b, Wr2b, 2);
    }
  }
  __syncthreads();
  const int node = blockIdx.x * 64 + threadIdx.x;
  const int nnz = cnt[node];
  const int bbase = node & ~(NN - 1);

  // ---- own-u and neighbor-sum msv
  float uself[NU], msv[NU];
  if (PHASE == 1) {
    // gather sum of (yh, hh) over neighbors: 8 B per neighbor
    float sy = 0.f, sh = 0.f;
#pragma unroll 4
    for (int t = 0; t < nnz; ++t) {
      const int j = (int)idxT[(size_t)t * NBN + node];
      float2 v = yhh[bbase + j];
      sy += v.x; sh += v.y;
    }
    const float2 w0 = yhh[node];
    const float fn = (float)nnz;
#pragma unroll
    for (int o = 0; o < NU; ++o) {
      uself[o] = w0.x * sW1[2 * o] + w0.y * sW1[2 * o + 1] + sWb1[o];
      msv[o] = sy * sW1[2 * o] + sh * sW1[2 * o + 1] + fn * sWb1[o];
    }
  } else {
    float4 acc0 = {0, 0, 0, 0}, acc1 = {0, 0, 0, 0};
#pragma unroll 4
    for (int t = 0; t < nnz; ++t) {
      const int j = (int)idxT[(size_t)t * NBN + node];
      const float4* up = (const float4*)(u_in + ((size_t)bbase + j) * NU);
      float4 a = up[0], c4 = up[1];
      acc0.x += a.x;  acc0.y += a.y;  acc0.z += a.z;  acc0.w += a.w;
      acc1.x += c4.x; acc1.y += c4.y; acc1.z += c4.z; acc1.w += c4.w;
    }
    msv[0] = acc0.x; msv[1] = acc0.y; msv[2] = acc0.z; msv[3] = acc0.w;
    msv[4] = acc1.x; msv[5] = acc1.y; msv[6] = acc1.z; msv[7] = acc1.w;
    const float4* up = (const float4*)(u_in + (size_t)node * NU);
    float4 a = up[0], c4 = up[1];
    uself[0] = a.x;  uself[1] = a.y;  uself[2] = a.z;  uself[3] = a.w;
    uself[4] = c4.x; uself[5] = c4.y; uself[6] = c4.z; uself[7] = c4.w;
  }

  // ---- msg MLP
  float agg[3 * NU];
  const float d = deg[node], e = eg[node];
#pragma unroll
  for (int o = 0; o < NU; ++o) {
    agg[o] = uself[o] * d;
    agg[NU + o] = msv[o];
    agg[2 * NU + o] = e;
  }
  float h1[NMLP];
#pragma unroll
  for (int h = 0; h < NMLP; ++h) {
    float t = sWm1b[h];
#pragma unroll
    for (int i = 0; i < 3 * NU; ++i) t += sWm1[h * 3 * NU + i] * agg[i];
    h1[h] = fmaxf(t, 0.f);
  }
  float x[NU + 2];
#pragma unroll
  for (int o = 0; o < NU; ++o) {
    float t = sWm2b[o];
#pragma unroll
    for (int h = 0; h < NMLP; ++h) t += sWm2[o * NMLP + h] * h1[h];
    x[o] = t;
  }
  x[NU] = rin[node];
  x[NU + 1] = fmaxf(nur[node], 1e-10f);

  // ---- GRU
  float sv[NH];
#pragma unroll
  for (int g = 0; g < NH; ++g)
    sv[g] = (PHASE == 1) ? 0.f : s[(size_t)node * NH + g];

  float sn[NH];
#pragma unroll
  for (int g = 0; g < NH; ++g) {
    float xr = sbih[g], xz = sbih[NH + g], xn = sbih[2 * NH + g];
#pragma unroll
    for (int i = 0; i < NU + 2; ++i) {
      xr += sgih[g * (NU + 2) + i] * x[i];
      xz += sgih[(NH + g) * (NU + 2) + i] * x[i];
      xn += sgih[(2 * NH + g) * (NU + 2) + i] * x[i];
    }
    float hr = sbhh[g], hz = sbhh[NH + g], hn = sbhh[2 * NH + g];
    if (PHASE != 1) {
#pragma unroll
      for (int i = 0; i < NH; ++i) {
        hr += sghh[g * NH + i] * sv[i];
        hz += sghh[(NH + g) * NH + i] * sv[i];
        hn += sghh[(2 * NH + g) * NH + i] * sv[i];
      }
    }
    float rg = 1.f / (1.f + expf(-(xr + hr)));
    float zg = 1.f / (1.f + expf(-(xz + hz)));
    float ng = tanhf(xn + rg * hn);
    sn[g] = (1.f - zg) * ng + zg * sv[g];
  }

  if (PHASE == 1) {
#pragma unroll
    for (int g = 0; g < NH; ++g) s[(size_t)node * NH + g] = sn[g];
  }

  // ---- W2
  float un[NU];
#pragma unroll
  for (int o = 0; o < NU; ++o) {
    float t = sW2b[o] + sb2[o];
#pragma unroll
    for (int h = 0; h < NH; ++h) t += sW2[o * NH + h] * sn[h];
    un[o] = t;
  }
  if (PHASE == 1) {
#pragma unroll
    for (int o = 0; o < NU; ++o) u_out[(size_t)node * NU + o] = un[o];
  }

  // ---- readout (PHASE 2 only)
  if (PHASE == 2) {
    float h2[NMLP];
#pragma unroll
    for (int h = 0; h < NMLP; ++h) {
      float t = sWr1b[h];
#pragma unroll
      for (int o = 0; o < NU; ++o) t += sWr1[h * NU + o] * un[o];
      h2[h] = fmaxf(t, 0.f);
    }
    float l0 = sWr2b[0], l1 = sWr2b[1];
#pragma unroll
    for (int h = 0; h < NMLP; ++h) {
      l0 += sWr2[h] * h2[h];
      l1 += sWr2[NMLP + h] * h2[h];
    }
    float mx = fmaxf(l0, l1);
    float e0 = expf(l0 - mx), e1 = expf(l1 - mx);
    float inv = 1.f / (e0 + e1);
    float p0 = e0 * inv, p1 = e1 * inv;
    const float q0 = -0.70710678118654752f, q1 = 0.70710678118654752f;
    float xh = p0 * q0 + p1 * q1;
    float nu = p0 * (q0 - xh) * (q0 - xh) + p1 * (q1 - xh) * (q1 - xh);
    out[node] = xh;
    out[NB * NN + node] = fmaxf(nu, 1e-10f);
  }
}

// ---------------------------------------------------------------------------
extern "C" void kernel_launch(void* const* d_in, const int* in_sizes, int n_in,
                              void* d_out, int out_size, void* d_ws,
                              size_t ws_size, hipStream_t stream) {
  const float* y    = (const float*)d_in[0];
  const float* H    = (const float*)d_in[1];
  const float* r    = (const float*)d_in[2];
  const float* nur  = (const float*)d_in[3];
  const float* adj  = (const float*)d_in[4];
  const float* W1w  = (const float*)d_in[5];
  const float* W1b  = (const float*)d_in[6];
  const float* b1   = (const float*)d_in[7];
  const float* Wm1w = (const float*)d_in[8];
  const float* Wm1b = (const float*)d_in[9];
  const float* Wm2w = (const float*)d_in[10];
  const float* Wm2b = (const float*)d_in[11];
  const float* gih  = (const float*)d_in[12];
  const float* ghh  = (const float*)d_in[13];
  const float* bih  = (const float*)d_in[14];
  const float* bhh  = (const float*)d_in[15];
  const float* W2w  = (const float*)d_in[16];
  const float* W2b  = (const float*)d_in[17];
  const float* b2   = (const float*)d_in[18];
  const float* Wr1w = (const float*)d_in[19];
  const float* Wr1b = (const float*)d_in[20];
  const float* Wr2w = (const float*)d_in[21];
  const float* Wr2b = (const float*)d_in[22];
  float* out = (float*)d_out;

  // workspace carve (all 256B aligned)
  char* p = (char*)d_ws;
  auto carve = [&](size_t bytes) {
    void* q = (void*)p;
    p += (bytes + 255) & ~(size_t)255;
    return q;
  };
  unsigned short* idxT = (unsigned short*)carve((size_t)MAXN * NBN * 2);  // 4 MB
  int*   cnt  = (int*)  carve((size_t)NBN * 4);
  float* deg  = (float*)carve((size_t)NBN * 4);
  float* eg   = (float*)carve((size_t)NBN * 4);
  float* yhh  = (float*)carve((size_t)NBN * 8);
  float* u    = (float*)carve((size_t)NBN * NU * 4);
  float* s    = (float*)carve((size_t)NBN * NH * 4);

  k_build_idx<<<NBN / 4, 256, 0, stream>>>(adj, idxT, cnt, deg, eg, yhh);
  k_eg<<<NB * NCHUNK, 512, 0, stream>>>(H, y, idxT, cnt, eg, yhh);

  k_iter<1><<<NBN / 64, 64, 0, stream>>>(
      u, (const float2*)yhh, idxT, cnt, deg, eg, r, nur, W1w, W1b, b1,
      Wm1w, Wm1b, Wm2w, Wm2b, gih, ghh, bih, bhh, W2w, W2b, b2,
      Wr1w, Wr1b, Wr2w, Wr2b, s, u, out);
  k_iter<2><<<NBN / 64, 64, 0, stream>>>(
      u, (const float2*)yhh, idxT, cnt, deg, eg, r, nur, W1w, W1b, b1,
      Wm1w, Wm1b, Wm2w, Wm2b, gih, ghh, bih, bhh, W2w, W2b, b2,
      Wr1w, Wr1b, Wr2w, Wr2b, s, u, out);
}